// Round 15
// baseline (340.515 us; speedup 1.0000x reference)
//
#include <hip/hip_runtime.h>

// Problem constants
#define NN   50000
#define EE   800000
#define VIN  128
#define HIDN 128
#define UIN  64
#define MEMN 128
#define CATN 320
#define LN_EPS 1e-5f
#define SCAN_NB 196

typedef __attribute__((ext_vector_type(8))) short short8;
typedef __attribute__((ext_vector_type(4))) float f32x4;
typedef __attribute__((ext_vector_type(4))) unsigned int uint4v;
typedef __attribute__((ext_vector_type(4))) unsigned short ushort4v;
typedef unsigned short ushort_t;

__device__ inline ushort_t f32_bf16(float f) {
    unsigned u = __float_as_uint(f);
    return (ushort_t)((u + 0x7FFFu + ((u >> 16) & 1u)) >> 16);
}
__device__ inline float bf16_f32(ushort_t h) {
    return __uint_as_float(((unsigned)h) << 16);
}
// pack f32 -> (bf16_hi << 16) | bf16_lo  with  f ~= hi + lo
__device__ inline unsigned pack_hl(float y) {
    unsigned u  = __float_as_uint(y);
    unsigned hi = (u + 0x7FFFu + ((u >> 16) & 1u)) & 0xFFFF0000u;
    float    lo = y - __uint_as_float(hi);
    unsigned v  = __float_as_uint(lo);
    unsigned l16 = ((v + 0x7FFFu + ((v >> 16) & 1u)) >> 16) & 0xFFFFu;
    return hi | l16;
}

// ---------------------------------------------------------------------------
// CSR build: histogram -> scan -> bucket fill
// ---------------------------------------------------------------------------
__global__ void hist_kernel(const int* __restrict__ edge_dst, int* __restrict__ count)
{
    int gid = blockIdx.x * 256 + threadIdx.x;
    if (gid < EE) atomicAdd(&count[edge_dst[gid]], 1);
}

__global__ void block_sum_kernel(const int* __restrict__ count, int* __restrict__ partials)
{
    __shared__ int s[256];
    const int tid = threadIdx.x;
    const int gid = blockIdx.x * 256 + tid;
    s[tid] = (gid < NN) ? count[gid] : 0;
    __syncthreads();
    for (int off = 128; off >= 1; off >>= 1) {
        if (tid < off) s[tid] += s[tid + off];
        __syncthreads();
    }
    if (tid == 0) partials[blockIdx.x] = s[0];
}

__global__ void scan_partials_kernel(int* __restrict__ partials)
{
    __shared__ int s[256];
    const int tid = threadIdx.x;
    const int v = (tid < SCAN_NB) ? partials[tid] : 0;
    s[tid] = v;
    __syncthreads();
    for (int off = 1; off < 256; off <<= 1) {
        int t = (tid >= off) ? s[tid - off] : 0;
        __syncthreads();
        s[tid] += t;
        __syncthreads();
    }
    if (tid < SCAN_NB) partials[tid] = s[tid] - v;   // exclusive
}

__global__ void make_offsets_kernel(const int* __restrict__ count,
                                    const int* __restrict__ partials,
                                    int* __restrict__ offsets)
{
    __shared__ int s[256];
    const int tid = threadIdx.x;
    const int gid = blockIdx.x * 256 + tid;
    const int v = (gid < NN) ? count[gid] : 0;
    s[tid] = v;
    __syncthreads();
    for (int off = 1; off < 256; off <<= 1) {
        int t = (tid >= off) ? s[tid - off] : 0;
        __syncthreads();
        s[tid] += t;
        __syncthreads();
    }
    if (gid < NN) offsets[gid] = partials[blockIdx.x] + s[tid] - v;  // exclusive
}

__global__ void fill_kernel(const int* __restrict__ edge_dst,
                            const int* __restrict__ offsets,
                            int* __restrict__ cursor,
                            int* __restrict__ bucket)
{
    int gid = blockIdx.x * 256 + threadIdx.x;
    if (gid >= EE) return;
    const int d = edge_dst[gid];
    const int p = atomicAdd(&cursor[d], 1);
    bucket[offsets[d] + p] = gid;
}

// ---------------------------------------------------------------------------
// Weight prep (merged, one launch): mk hi/lo planes + transposed mv/w1/w2
// ---------------------------------------------------------------------------
__global__ void prep_all_kernel(const float* __restrict__ Mk,
                                const float* __restrict__ Mv,
                                const float* __restrict__ W1,
                                const float* __restrict__ W2,
                                ushort_t* __restrict__ mk_hi,
                                ushort_t* __restrict__ mk_lo,
                                ushort_t* __restrict__ mv_t,
                                ushort_t* __restrict__ w1_t,
                                ushort_t* __restrict__ w2_t)
{
    int i = blockIdx.x * 256 + threadIdx.x;
    if (i < MEMN * CATN) {                                // mk hi/lo planes
        const float f = Mk[i];
        const ushort_t h = f32_bf16(f);
        mk_hi[i] = h;
        mk_lo[i] = f32_bf16(f - bf16_f32(h));
    }
    if (i < CATN * MEMN) {                                // mv_t[c][m] = Mv[m][c]
        const int c = i >> 7, m = i & 127;
        mv_t[i] = f32_bf16(Mv[m * CATN + c]);
    }
    if (i < HIDN * CATN) {                                // w1_t[n][k] = W1[k][n]
        const int n = i / CATN, k = i - n * CATN;
        w1_t[i] = f32_bf16(W1[k * HIDN + n]);
    }
    if (i < HIDN * HIDN) {                                // w2_t[n][k] = W2[k][n]
        const int n = i >> 7, k = i & 127;
        w2_t[i] = f32_bf16(W2[k * HIDN + n]);
    }
}

// ---------------------------------------------------------------------------
// gather + LayerNorm + hi|lo pack: one wave per node (edge loop unrolled 8x,
// x/u/gamma/beta loads hoisted ahead of the edge loop)
// ---------------------------------------------------------------------------
__global__ __launch_bounds__(256) void gather_ln_kernel(
    const float* __restrict__ edge_attr,
    const int*   __restrict__ bucket,
    const int*   __restrict__ offsets,
    const int*   __restrict__ count,
    const float* __restrict__ x,
    const float* __restrict__ u,
    const int*   __restrict__ batch,
    const float* __restrict__ gamma,
    const float* __restrict__ beta,
    unsigned*    __restrict__ ln_pk)
{
    const int wid  = (blockIdx.x * 256 + threadIdx.x) >> 6;   // node id
    const int lane = threadIdx.x & 63;
    if (wid >= NN) return;

    // hoisted independent loads: latency overlaps the edge loop
    const float2 xv = reinterpret_cast<const float2*>(x)[(size_t)wid * 64 + lane];
    const float  uv = u[batch[wid] * UIN + lane];
    const float2 g0 = reinterpret_cast<const float2*>(gamma)[lane];
    const float2 g1 = reinterpret_cast<const float2*>(gamma)[64 + lane];
    const float  g2 = gamma[256 + lane];
    const float2 t0 = reinterpret_cast<const float2*>(beta)[lane];
    const float2 t1 = reinterpret_cast<const float2*>(beta)[64 + lane];
    const float  t2 = beta[256 + lane];

    const int start = offsets[wid];
    const int deg   = count[wid];
    const float2* ea2 = reinterpret_cast<const float2*>(edge_attr);
    float2 a = make_float2(0.f, 0.f);
    int i = 0;
    const int d8 = deg & ~7;
    for (; i < d8; i += 8) {                      // 8 independent row loads in flight
        const int e0 = bucket[start + i];
        const int e1 = bucket[start + i + 1];
        const int e2 = bucket[start + i + 2];
        const int e3 = bucket[start + i + 3];
        const int e4 = bucket[start + i + 4];
        const int e5 = bucket[start + i + 5];
        const int e6 = bucket[start + i + 6];
        const int e7 = bucket[start + i + 7];
        const float2 v0 = ea2[(size_t)e0 * 64 + lane];
        const float2 v1 = ea2[(size_t)e1 * 64 + lane];
        const float2 v2 = ea2[(size_t)e2 * 64 + lane];
        const float2 v3 = ea2[(size_t)e3 * 64 + lane];
        const float2 v4 = ea2[(size_t)e4 * 64 + lane];
        const float2 v5 = ea2[(size_t)e5 * 64 + lane];
        const float2 v6 = ea2[(size_t)e6 * 64 + lane];
        const float2 v7 = ea2[(size_t)e7 * 64 + lane];
        a.x += ((v0.x + v1.x) + (v2.x + v3.x)) + ((v4.x + v5.x) + (v6.x + v7.x));
        a.y += ((v0.y + v1.y) + (v2.y + v3.y)) + ((v4.y + v5.y) + (v6.y + v7.y));
    }
    const int d4 = deg & ~3;
    for (; i < d4; i += 4) {
        const int e0 = bucket[start + i];
        const int e1 = bucket[start + i + 1];
        const int e2 = bucket[start + i + 2];
        const int e3 = bucket[start + i + 3];
        const float2 v0 = ea2[(size_t)e0 * 64 + lane];
        const float2 v1 = ea2[(size_t)e1 * 64 + lane];
        const float2 v2 = ea2[(size_t)e2 * 64 + lane];
        const float2 v3 = ea2[(size_t)e3 * 64 + lane];
        a.x += (v0.x + v1.x) + (v2.x + v3.x);
        a.y += (v0.y + v1.y) + (v2.y + v3.y);
    }
    for (; i < deg; ++i) {
        const int e = bucket[start + i];
        const float2 v = ea2[(size_t)e * 64 + lane];
        a.x += v.x;
        a.y += v.y;
    }

    float s = xv.x + xv.y + a.x + a.y + uv;
    float q = xv.x * xv.x + xv.y * xv.y + a.x * a.x + a.y * a.y + uv * uv;
    #pragma unroll
    for (int off = 32; off >= 1; off >>= 1) {
        s += __shfl_xor(s, off);
        q += __shfl_xor(q, off);
    }
    const float mu  = s * (1.0f / CATN);
    const float var = q * (1.0f / CATN) - mu * mu;
    const float rs  = rsqrtf(var + LN_EPS);

    unsigned* row = ln_pk + (size_t)wid * CATN;
    uint2 p01, p23;
    p01.x = pack_hl((xv.x - mu) * rs * g0.x + t0.x);
    p01.y = pack_hl((xv.y - mu) * rs * g0.y + t0.y);
    p23.x = pack_hl((a.x - mu) * rs * g1.x + t1.x);
    p23.y = pack_hl((a.y - mu) * rs * g1.y + t1.y);
    reinterpret_cast<uint2*>(row)[lane]       = p01;      // cols 2l, 2l+1
    reinterpret_cast<uint2*>(row + 128)[lane] = p23;      // cols 128+2l, 129+2l
    row[256 + lane] = pack_hl((uv - mu) * rs * g2 + t2);  // col 256+l
}

// ---------------------------------------------------------------------------
// Fused MFMA kernel: 16 nodes/block, 256 threads (4 waves), 25.9 KB LDS
// -> 6 blocks/CU (24 waves/CU). Same per-wave structure as the verified
// 32-node kernel with the node-tile dimension halved.
// ---------------------------------------------------------------------------
#define MSTR 328            // bf16 row stride: 656B = 41 x 16B (8B-aligned rows)
#define PSTR 136            // bf16 row stride: 272B = 17 x 16B

__global__ __launch_bounds__(256) void node_mfma_kernel(
    const unsigned* __restrict__ ln_pk,
    const ushort_t* __restrict__ mk_hi,
    const ushort_t* __restrict__ mk_lo,
    const ushort_t* __restrict__ mv_t,
    const ushort_t* __restrict__ w1_t,
    const ushort_t* __restrict__ w2_t,
    const float*    __restrict__ b1,
    const float*    __restrict__ b2,
    float*          __restrict__ out)
{
    __shared__ __align__(16) ushort_t s_lnh[16 * MSTR];   // ln hi -> later mix
    __shared__ __align__(16) ushort_t s_lnl[16 * MSTR];   // ln lo
    __shared__ __align__(16) ushort_t s_P[16 * PSTR];     // attn bf16 -> later h
    __shared__ __align__(16) float2   s_part[4 * 16];     // per-(wave,node) {max,sum}

    const int tid  = threadIdx.x;
    const int wv   = tid >> 6;
    const int lane = tid & 63;
    const int l15  = lane & 15;
    const int l4   = lane >> 4;
    const int node0 = blockIdx.x * 16;

    const f32x4 zero4 = {0.f, 0.f, 0.f, 0.f};

    // ---- stage: ln_pk (16 rows) -> s_lnh / s_lnl, split once (b64 writes) ----
    for (int j = tid; j < 16 * 80; j += 256) {
        const int nl = j / 80;
        const int c0 = (j - nl * 80) * 4;
        const int ng = node0 + nl;                        // 50000 = 3125*16, in range
        const uint4v p = *(const uint4v*)(ln_pk + (size_t)ng * CATN + c0);
        ushort4v h4, l4v;
        h4.x = (ushort_t)(p.x >> 16);  l4v.x = (ushort_t)(p.x & 0xFFFFu);
        h4.y = (ushort_t)(p.y >> 16);  l4v.y = (ushort_t)(p.y & 0xFFFFu);
        h4.z = (ushort_t)(p.z >> 16);  l4v.z = (ushort_t)(p.z & 0xFFFFu);
        h4.w = (ushort_t)(p.w >> 16);  l4v.w = (ushort_t)(p.w & 0xFFFFu);
        *(ushort4v*)(s_lnh + nl * MSTR + c0) = h4;        // 656B rows are 8B-aligned
        *(ushort4v*)(s_lnl + nl * MSTR + c0) = l4v;
    }
    __syncthreads();

    // ===== P1 (swapped): A = Mk rows (D-row = m), B = ln (D-col = node)
    //       wave wv owns m-tiles wv*2, wv*2+1; lane holds S[m][node = l15]
    {
        f32x4 acc[2];   // [ai = m-tile]
        acc[0] = zero4; acc[1] = zero4;

        #pragma unroll 2
        for (int kc = 0; kc < 10; ++kc) {
            const int koff = kc * 32 + l4 * 8;
            short8 amh[2], aml[2];
            #pragma unroll
            for (int ai = 0; ai < 2; ++ai) {
                const int mr = (wv * 2 + ai) * 16 + l15;
                amh[ai] = *(const short8*)(mk_hi + (size_t)mr * CATN + koff);
                aml[ai] = *(const short8*)(mk_lo + (size_t)mr * CATN + koff);
            }
            const short8 bnh = *(const short8*)(s_lnh + l15 * MSTR + koff);
            const short8 bnl = *(const short8*)(s_lnl + l15 * MSTR + koff);
            #pragma unroll
            for (int ai = 0; ai < 2; ++ai) {
                acc[ai] = __builtin_amdgcn_mfma_f32_16x16x32_bf16(amh[ai], bnh, acc[ai], 0, 0, 0);
                acc[ai] = __builtin_amdgcn_mfma_f32_16x16x32_bf16(aml[ai], bnh, acc[ai], 0, 0, 0);
                acc[ai] = __builtin_amdgcn_mfma_f32_16x16x32_bf16(amh[ai], bnl, acc[ai], 0, 0, 0);
            }
        }

        // ---- in-register softmax over m (128) per node ----
        float mx = acc[0][0];
        #pragma unroll
        for (int ai = 0; ai < 2; ++ai)
            #pragma unroll
            for (int r = 0; r < 4; ++r) mx = fmaxf(mx, acc[ai][r]);
        mx = fmaxf(mx, __shfl_xor(mx, 16));
        mx = fmaxf(mx, __shfl_xor(mx, 32));
        float sm = 0.f;
        #pragma unroll
        for (int ai = 0; ai < 2; ++ai)
            #pragma unroll
            for (int r = 0; r < 4; ++r) sm += __expf(acc[ai][r] - mx);
        sm += __shfl_xor(sm, 16);
        sm += __shfl_xor(sm, 32);
        if (l4 == 0) s_part[wv * 16 + l15] = make_float2(mx, sm);
        __syncthreads();

        const float2 p0 = s_part[0 * 16 + l15];
        const float2 p1 = s_part[1 * 16 + l15];
        const float2 p2 = s_part[2 * 16 + l15];
        const float2 p3 = s_part[3 * 16 + l15];
        const float mg = fmaxf(fmaxf(p0.x, p1.x), fmaxf(p2.x, p3.x));
        const float sg = p0.y * __expf(p0.x - mg) + p1.y * __expf(p1.x - mg)
                       + p2.y * __expf(p2.x - mg) + p3.y * __expf(p3.x - mg);
        const float inv = 1.f / sg;
        ushort_t* prow = s_P + l15 * PSTR + (wv * 2) * 16 + l4 * 4;
        #pragma unroll
        for (int ai = 0; ai < 2; ++ai)
            #pragma unroll
            for (int r = 0; r < 4; ++r)
                prow[ai * 16 + r] = f32_bf16(__expf(acc[ai][r] - mg) * inv);
    }
    __syncthreads();

    // ====== PV: attn = P @ Mv (N=320); mix = 0.5*(attn+ln) -> s_lnh =========
    {
        f32x4 acc[5];
        #pragma unroll
        for (int nn = 0; nn < 5; ++nn) acc[nn] = zero4;

        #pragma unroll
        for (int kc = 0; kc < 4; ++kc) {
            const int koff = kc * 32 + l4 * 8;
            const short8 ap = *(const short8*)(s_P + l15 * PSTR + koff);
            short8 bv[5];
            #pragma unroll
            for (int nn = 0; nn < 5; ++nn) {
                const int c = (wv * 5 + nn) * 16 + l15;
                bv[nn] = *(const short8*)(mv_t + (size_t)c * MEMN + koff);
            }
            #pragma unroll
            for (int nn = 0; nn < 5; ++nn)
                acc[nn] = __builtin_amdgcn_mfma_f32_16x16x32_bf16(ap, bv[nn], acc[nn], 0, 0, 0);
        }
        // mix: unique owner lane per (node,c) -> in-place safe. lnv = hi + lo.
        #pragma unroll
        for (int nn = 0; nn < 5; ++nn)
            #pragma unroll
            for (int r = 0; r < 4; ++r) {
                const int node_l = l4 * 4 + r;
                const int c = (wv * 5 + nn) * 16 + l15;
                const int idx = node_l * MSTR + c;
                const float lnv = bf16_f32(s_lnh[idx]) + bf16_f32(s_lnl[idx]);
                s_lnh[idx] = f32_bf16(0.5f * (acc[nn][r] + lnv));
            }
    }
    __syncthreads();

    // ================= W1: h = relu(mix @ W1 + b1) -> s_P ====================
    {
        f32x4 acc[2];
        acc[0] = zero4; acc[1] = zero4;

        #pragma unroll 2
        for (int kc = 0; kc < 10; ++kc) {
            const int koff = kc * 32 + l4 * 8;
            const short8 am = *(const short8*)(s_lnh + l15 * MSTR + koff);
            short8 bw[2];
            #pragma unroll
            for (int nt = 0; nt < 2; ++nt) {
                const int n = (wv * 2 + nt) * 16 + l15;
                bw[nt] = *(const short8*)(w1_t + (size_t)n * CATN + koff);
            }
            #pragma unroll
            for (int nt = 0; nt < 2; ++nt)
                acc[nt] = __builtin_amdgcn_mfma_f32_16x16x32_bf16(am, bw[nt], acc[nt], 0, 0, 0);
        }
        float bb[2];
        #pragma unroll
        for (int nt = 0; nt < 2; ++nt) bb[nt] = b1[(wv * 2 + nt) * 16 + l15];
        __syncthreads();   // all W1 A-reads done before s_P region is reused as h
        #pragma unroll
        for (int nt = 0; nt < 2; ++nt)
            #pragma unroll
            for (int r = 0; r < 4; ++r) {
                const int node_l = l4 * 4 + r;
                const int col = (wv * 2 + nt) * 16 + l15;
                s_P[node_l * PSTR + col] = f32_bf16(fmaxf(acc[nt][r] + bb[nt], 0.f));
            }
    }
    __syncthreads();

    // ================= W2: y = h @ W2 + b2 -> out ============================
    {
        f32x4 acc[2];
        acc[0] = zero4; acc[1] = zero4;

        #pragma unroll
        for (int kc = 0; kc < 4; ++kc) {
            const int koff = kc * 32 + l4 * 8;
            const short8 ah = *(const short8*)(s_P + l15 * PSTR + koff);
            short8 bw[2];
            #pragma unroll
            for (int nt = 0; nt < 2; ++nt) {
                const int n = (wv * 2 + nt) * 16 + l15;
                bw[nt] = *(const short8*)(w2_t + (size_t)n * HIDN + koff);
            }
            #pragma unroll
            for (int nt = 0; nt < 2; ++nt)
                acc[nt] = __builtin_amdgcn_mfma_f32_16x16x32_bf16(ah, bw[nt], acc[nt], 0, 0, 0);
        }
        float bb[2];
        #pragma unroll
        for (int nt = 0; nt < 2; ++nt) bb[nt] = b2[(wv * 2 + nt) * 16 + l15];
        #pragma unroll
        for (int nt = 0; nt < 2; ++nt)
            #pragma unroll
            for (int r = 0; r < 4; ++r) {
                const int ng = node0 + l4 * 4 + r;
                if (ng < NN) {
                    const int col = (wv * 2 + nt) * 16 + l15;
                    out[(size_t)ng * HIDN + col] = acc[nt][r] + bb[nt];
                }
            }
    }
}

// ---------------------------------------------------------------------------
extern "C" void kernel_launch(void* const* d_in, const int* in_sizes, int n_in,
                              void* d_out, int out_size, void* d_ws, size_t ws_size,
                              hipStream_t stream)
{
    const float* x         = (const float*)d_in[0];
    const int*   edge_idx  = (const int*)  d_in[1];   // [2,E] int32
    const float* edge_attr = (const float*)d_in[2];
    const float* u         = (const float*)d_in[3];
    const int*   batch     = (const int*)  d_in[4];
    const float* Mk        = (const float*)d_in[5];
    const float* Mv        = (const float*)d_in[6];
    const float* gamma     = (const float*)d_in[7];
    const float* beta      = (const float*)d_in[8];
    const float* W1        = (const float*)d_in[9];
    const float* b1        = (const float*)d_in[10];
    const float* W2        = (const float*)d_in[11];
    const float* b2        = (const float*)d_in[12];
    float*       out       = (float*)d_out;

    // ws layout
    char* w = (char*)d_ws;
    int*   count     = (int*)w;        w += (size_t)NN * sizeof(int);
    int*   cursor    = (int*)w;        w += (size_t)NN * sizeof(int);
    int*   offsets   = (int*)w;        w += (size_t)NN * sizeof(int);
    int*   partials  = (int*)w;        w += 256 * sizeof(int);
    int*   bucket    = (int*)w;        w += (size_t)EE * sizeof(int);              // 3.2 MB
    w = (char*)(((size_t)w + 255) & ~(size_t)255);
    unsigned* ln_pk  = (unsigned*)w;   w += (size_t)NN * CATN * sizeof(unsigned);  // 64 MB
    ushort_t* mk_hi  = (ushort_t*)w;   w += (size_t)MEMN * CATN * 2;
    ushort_t* mk_lo  = (ushort_t*)w;   w += (size_t)MEMN * CATN * 2;
    ushort_t* mv_t   = (ushort_t*)w;   w += (size_t)CATN * MEMN * 2;
    ushort_t* w1_t   = (ushort_t*)w;   w += (size_t)HIDN * CATN * 2;
    ushort_t* w2_t   = (ushort_t*)w;   w += (size_t)HIDN * HIDN * 2;

    const int* edge_dst = edge_idx + EE;         // row 1 of edge_index

    hipMemsetAsync(count, 0, (size_t)2 * NN * sizeof(int), stream);

    const int eb = (EE + 255) / 256;
    hist_kernel<<<eb, 256, 0, stream>>>(edge_dst, count);
    block_sum_kernel<<<SCAN_NB, 256, 0, stream>>>(count, partials);
    scan_partials_kernel<<<1, 256, 0, stream>>>(partials);
    make_offsets_kernel<<<SCAN_NB, 256, 0, stream>>>(count, partials, offsets);
    fill_kernel<<<eb, 256, 0, stream>>>(edge_dst, offsets, cursor, bucket);

    prep_all_kernel<<<(HIDN * CATN + 255) / 256, 256, 0, stream>>>(
        Mk, Mv, W1, W2, mk_hi, mk_lo, mv_t, w1_t, w2_t);

    gather_ln_kernel<<<(NN * 64 + 255) / 256, 256, 0, stream>>>(
        edge_attr, bucket, offsets, count, x, u, batch, gamma, beta, ln_pk);

    node_mfma_kernel<<<NN / 16, 256, 0, stream>>>(
        ln_pk, mk_hi, mk_lo, mv_t, w1_t, w2_t, b1, b2, out);
}

// Round 16
// 292.653 us; speedup vs baseline: 1.1635x; 1.1635x over previous
//
#include <hip/hip_runtime.h>

// Problem constants
#define NN   50000
#define EE   800000
#define VIN  128
#define HIDN 128
#define UIN  64
#define MEMN 128
#define CATN 320
#define LN_EPS 1e-5f
#define SCAN_NB 196

typedef __attribute__((ext_vector_type(8))) short short8;
typedef __attribute__((ext_vector_type(4))) float f32x4;
typedef __attribute__((ext_vector_type(4))) unsigned int uint4v;
typedef __attribute__((ext_vector_type(4))) unsigned short ushort4v;
typedef unsigned short ushort_t;

__device__ inline ushort_t f32_bf16(float f) {
    unsigned u = __float_as_uint(f);
    return (ushort_t)((u + 0x7FFFu + ((u >> 16) & 1u)) >> 16);
}
__device__ inline float bf16_f32(ushort_t h) {
    return __uint_as_float(((unsigned)h) << 16);
}
// pack f32 -> (bf16_hi << 16) | bf16_lo  with  f ~= hi + lo
__device__ inline unsigned pack_hl(float y) {
    unsigned u  = __float_as_uint(y);
    unsigned hi = (u + 0x7FFFu + ((u >> 16) & 1u)) & 0xFFFF0000u;
    float    lo = y - __uint_as_float(hi);
    unsigned v  = __float_as_uint(lo);
    unsigned l16 = ((v + 0x7FFFu + ((v >> 16) & 1u)) >> 16) & 0xFFFFu;
    return hi | l16;
}

// ---------------------------------------------------------------------------
// CSR build: histogram -> scan -> bucket fill
// ---------------------------------------------------------------------------
__global__ void hist_kernel(const int* __restrict__ edge_dst, int* __restrict__ count)
{
    int gid = blockIdx.x * 256 + threadIdx.x;
    if (gid < EE) atomicAdd(&count[edge_dst[gid]], 1);
}

__global__ void block_sum_kernel(const int* __restrict__ count, int* __restrict__ partials)
{
    __shared__ int s[256];
    const int tid = threadIdx.x;
    const int gid = blockIdx.x * 256 + tid;
    s[tid] = (gid < NN) ? count[gid] : 0;
    __syncthreads();
    for (int off = 128; off >= 1; off >>= 1) {
        if (tid < off) s[tid] += s[tid + off];
        __syncthreads();
    }
    if (tid == 0) partials[blockIdx.x] = s[0];
}

__global__ void scan_partials_kernel(int* __restrict__ partials)
{
    __shared__ int s[256];
    const int tid = threadIdx.x;
    const int v = (tid < SCAN_NB) ? partials[tid] : 0;
    s[tid] = v;
    __syncthreads();
    for (int off = 1; off < 256; off <<= 1) {
        int t = (tid >= off) ? s[tid - off] : 0;
        __syncthreads();
        s[tid] += t;
        __syncthreads();
    }
    if (tid < SCAN_NB) partials[tid] = s[tid] - v;   // exclusive
}

__global__ void make_offsets_kernel(const int* __restrict__ count,
                                    const int* __restrict__ partials,
                                    int* __restrict__ offsets)
{
    __shared__ int s[256];
    const int tid = threadIdx.x;
    const int gid = blockIdx.x * 256 + tid;
    const int v = (gid < NN) ? count[gid] : 0;
    s[tid] = v;
    __syncthreads();
    for (int off = 1; off < 256; off <<= 1) {
        int t = (tid >= off) ? s[tid - off] : 0;
        __syncthreads();
        s[tid] += t;
        __syncthreads();
    }
    if (gid < NN) offsets[gid] = partials[blockIdx.x] + s[tid] - v;  // exclusive
}

__global__ void fill_kernel(const int* __restrict__ edge_dst,
                            const int* __restrict__ offsets,
                            int* __restrict__ cursor,
                            int* __restrict__ bucket)
{
    int gid = blockIdx.x * 256 + threadIdx.x;
    if (gid >= EE) return;
    const int d = edge_dst[gid];
    const int p = atomicAdd(&cursor[d], 1);
    bucket[offsets[d] + p] = gid;
}

// ---------------------------------------------------------------------------
// Weight prep (merged, one launch): mk hi/lo planes + transposed mv/w1/w2
// ---------------------------------------------------------------------------
__global__ void prep_all_kernel(const float* __restrict__ Mk,
                                const float* __restrict__ Mv,
                                const float* __restrict__ W1,
                                const float* __restrict__ W2,
                                ushort_t* __restrict__ mk_hi,
                                ushort_t* __restrict__ mk_lo,
                                ushort_t* __restrict__ mv_t,
                                ushort_t* __restrict__ w1_t,
                                ushort_t* __restrict__ w2_t)
{
    int i = blockIdx.x * 256 + threadIdx.x;
    if (i < MEMN * CATN) {                                // mk hi/lo planes
        const float f = Mk[i];
        const ushort_t h = f32_bf16(f);
        mk_hi[i] = h;
        mk_lo[i] = f32_bf16(f - bf16_f32(h));
    }
    if (i < CATN * MEMN) {                                // mv_t[c][m] = Mv[m][c]
        const int c = i >> 7, m = i & 127;
        mv_t[i] = f32_bf16(Mv[m * CATN + c]);
    }
    if (i < HIDN * CATN) {                                // w1_t[n][k] = W1[k][n]
        const int n = i / CATN, k = i - n * CATN;
        w1_t[i] = f32_bf16(W1[k * HIDN + n]);
    }
    if (i < HIDN * HIDN) {                                // w2_t[n][k] = W2[k][n]
        const int n = i >> 7, k = i & 127;
        w2_t[i] = f32_bf16(W2[k * HIDN + n]);
    }
}

// ---------------------------------------------------------------------------
// gather + LayerNorm + hi|lo pack: one wave per node (edge loop unrolled 8x,
// x/u/gamma/beta loads hoisted ahead of the edge loop)
// ---------------------------------------------------------------------------
__global__ __launch_bounds__(256) void gather_ln_kernel(
    const float* __restrict__ edge_attr,
    const int*   __restrict__ bucket,
    const int*   __restrict__ offsets,
    const int*   __restrict__ count,
    const float* __restrict__ x,
    const float* __restrict__ u,
    const int*   __restrict__ batch,
    const float* __restrict__ gamma,
    const float* __restrict__ beta,
    unsigned*    __restrict__ ln_pk)
{
    const int wid  = (blockIdx.x * 256 + threadIdx.x) >> 6;   // node id
    const int lane = threadIdx.x & 63;
    if (wid >= NN) return;

    // hoisted independent loads: latency overlaps the edge loop
    const float2 xv = reinterpret_cast<const float2*>(x)[(size_t)wid * 64 + lane];
    const float  uv = u[batch[wid] * UIN + lane];
    const float2 g0 = reinterpret_cast<const float2*>(gamma)[lane];
    const float2 g1 = reinterpret_cast<const float2*>(gamma)[64 + lane];
    const float  g2 = gamma[256 + lane];
    const float2 t0 = reinterpret_cast<const float2*>(beta)[lane];
    const float2 t1 = reinterpret_cast<const float2*>(beta)[64 + lane];
    const float  t2 = beta[256 + lane];

    const int start = offsets[wid];
    const int deg   = count[wid];
    const float2* ea2 = reinterpret_cast<const float2*>(edge_attr);
    float2 a = make_float2(0.f, 0.f);
    int i = 0;
    const int d8 = deg & ~7;
    for (; i < d8; i += 8) {                      // 8 independent row loads in flight
        const int e0 = bucket[start + i];
        const int e1 = bucket[start + i + 1];
        const int e2 = bucket[start + i + 2];
        const int e3 = bucket[start + i + 3];
        const int e4 = bucket[start + i + 4];
        const int e5 = bucket[start + i + 5];
        const int e6 = bucket[start + i + 6];
        const int e7 = bucket[start + i + 7];
        const float2 v0 = ea2[(size_t)e0 * 64 + lane];
        const float2 v1 = ea2[(size_t)e1 * 64 + lane];
        const float2 v2 = ea2[(size_t)e2 * 64 + lane];
        const float2 v3 = ea2[(size_t)e3 * 64 + lane];
        const float2 v4 = ea2[(size_t)e4 * 64 + lane];
        const float2 v5 = ea2[(size_t)e5 * 64 + lane];
        const float2 v6 = ea2[(size_t)e6 * 64 + lane];
        const float2 v7 = ea2[(size_t)e7 * 64 + lane];
        a.x += ((v0.x + v1.x) + (v2.x + v3.x)) + ((v4.x + v5.x) + (v6.x + v7.x));
        a.y += ((v0.y + v1.y) + (v2.y + v3.y)) + ((v4.y + v5.y) + (v6.y + v7.y));
    }
    const int d4 = deg & ~3;
    for (; i < d4; i += 4) {
        const int e0 = bucket[start + i];
        const int e1 = bucket[start + i + 1];
        const int e2 = bucket[start + i + 2];
        const int e3 = bucket[start + i + 3];
        const float2 v0 = ea2[(size_t)e0 * 64 + lane];
        const float2 v1 = ea2[(size_t)e1 * 64 + lane];
        const float2 v2 = ea2[(size_t)e2 * 64 + lane];
        const float2 v3 = ea2[(size_t)e3 * 64 + lane];
        a.x += (v0.x + v1.x) + (v2.x + v3.x);
        a.y += (v0.y + v1.y) + (v2.y + v3.y);
    }
    for (; i < deg; ++i) {
        const int e = bucket[start + i];
        const float2 v = ea2[(size_t)e * 64 + lane];
        a.x += v.x;
        a.y += v.y;
    }

    float s = xv.x + xv.y + a.x + a.y + uv;
    float q = xv.x * xv.x + xv.y * xv.y + a.x * a.x + a.y * a.y + uv * uv;
    #pragma unroll
    for (int off = 32; off >= 1; off >>= 1) {
        s += __shfl_xor(s, off);
        q += __shfl_xor(q, off);
    }
    const float mu  = s * (1.0f / CATN);
    const float var = q * (1.0f / CATN) - mu * mu;
    const float rs  = rsqrtf(var + LN_EPS);

    unsigned* row = ln_pk + (size_t)wid * CATN;
    uint2 p01, p23;
    p01.x = pack_hl((xv.x - mu) * rs * g0.x + t0.x);
    p01.y = pack_hl((xv.y - mu) * rs * g0.y + t0.y);
    p23.x = pack_hl((a.x - mu) * rs * g1.x + t1.x);
    p23.y = pack_hl((a.y - mu) * rs * g1.y + t1.y);
    reinterpret_cast<uint2*>(row)[lane]       = p01;      // cols 2l, 2l+1
    reinterpret_cast<uint2*>(row + 128)[lane] = p23;      // cols 128+2l, 129+2l
    row[256 + lane] = pack_hl((uv - mu) * rs * g2 + t2);  // col 256+l
}

// ---------------------------------------------------------------------------
// Fused MFMA kernel: swapped-operand scores + in-register softmax.
// 32 nodes/block, 256 threads (4 waves). 51.6 KB LDS -> 3 blocks/CU.
// ---------------------------------------------------------------------------
#define MSTR 328            // bf16 row stride: 656B = 41 x 16B (8B-aligned rows)
#define PSTR 136            // bf16 row stride: 272B = 17 x 16B

__global__ __launch_bounds__(256) void node_mfma_kernel(
    const unsigned* __restrict__ ln_pk,
    const ushort_t* __restrict__ mk_hi,
    const ushort_t* __restrict__ mk_lo,
    const ushort_t* __restrict__ mv_t,
    const ushort_t* __restrict__ w1_t,
    const ushort_t* __restrict__ w2_t,
    const float*    __restrict__ b1,
    const float*    __restrict__ b2,
    float*          __restrict__ out)
{
    __shared__ __align__(16) ushort_t s_lnh[32 * MSTR];   // ln hi -> later mix
    __shared__ __align__(16) ushort_t s_lnl[32 * MSTR];   // ln lo
    __shared__ __align__(16) ushort_t s_P[32 * PSTR];     // attn bf16 -> later h
    __shared__ __align__(16) float2   s_part[8 * 16];     // per-(wave,node-tile) {max,sum}

    const int tid  = threadIdx.x;
    const int wv   = tid >> 6;
    const int lane = tid & 63;
    const int l15  = lane & 15;
    const int l4   = lane >> 4;
    const int node0 = blockIdx.x * 32;

    const f32x4 zero4 = {0.f, 0.f, 0.f, 0.f};

    // ---- stage: ln_pk (32 rows) -> s_lnh / s_lnl, split once (b64 writes) ----
    for (int j = tid; j < 32 * 80; j += 256) {
        const int nl = j / 80;
        const int c0 = (j - nl * 80) * 4;
        int ng = node0 + nl; ng = (ng < NN) ? ng : (NN - 1);
        const uint4v p = *(const uint4v*)(ln_pk + (size_t)ng * CATN + c0);
        ushort4v h4, l4v;
        h4.x = (ushort_t)(p.x >> 16);  l4v.x = (ushort_t)(p.x & 0xFFFFu);
        h4.y = (ushort_t)(p.y >> 16);  l4v.y = (ushort_t)(p.y & 0xFFFFu);
        h4.z = (ushort_t)(p.z >> 16);  l4v.z = (ushort_t)(p.z & 0xFFFFu);
        h4.w = (ushort_t)(p.w >> 16);  l4v.w = (ushort_t)(p.w & 0xFFFFu);
        *(ushort4v*)(s_lnh + nl * MSTR + c0) = h4;        // 656B rows are 8B-aligned
        *(ushort4v*)(s_lnl + nl * MSTR + c0) = l4v;
    }
    __syncthreads();

    // ===== P1 (swapped): S^T tile — A = Mk rows (D-row = m), B = ln (D-col = node)
    //       lane holds S[m = (wv*2+ai)*16 + l4*4 + r][node = bt*16 + l15]
    {
        f32x4 acc[2][2];   // [ai = m-tile][bt = node-tile]
        #pragma unroll
        for (int ai = 0; ai < 2; ++ai)
            #pragma unroll
            for (int bt = 0; bt < 2; ++bt) acc[ai][bt] = zero4;

        #pragma unroll 2
        for (int kc = 0; kc < 10; ++kc) {
            const int koff = kc * 32 + l4 * 8;
            short8 amh[2], aml[2], bnh[2], bnl[2];
            #pragma unroll
            for (int ai = 0; ai < 2; ++ai) {
                const int mr = (wv * 2 + ai) * 16 + l15;
                amh[ai] = *(const short8*)(mk_hi + (size_t)mr * CATN + koff);
                aml[ai] = *(const short8*)(mk_lo + (size_t)mr * CATN + koff);
            }
            #pragma unroll
            for (int bt = 0; bt < 2; ++bt) {
                bnh[bt] = *(const short8*)(s_lnh + (bt * 16 + l15) * MSTR + koff);
                bnl[bt] = *(const short8*)(s_lnl + (bt * 16 + l15) * MSTR + koff);
            }
            #pragma unroll
            for (int ai = 0; ai < 2; ++ai)
                #pragma unroll
                for (int bt = 0; bt < 2; ++bt) {
                    acc[ai][bt] = __builtin_amdgcn_mfma_f32_16x16x32_bf16(amh[ai], bnh[bt], acc[ai][bt], 0, 0, 0);
                    acc[ai][bt] = __builtin_amdgcn_mfma_f32_16x16x32_bf16(aml[ai], bnh[bt], acc[ai][bt], 0, 0, 0);
                    acc[ai][bt] = __builtin_amdgcn_mfma_f32_16x16x32_bf16(amh[ai], bnl[bt], acc[ai][bt], 0, 0, 0);
                }
        }

        // ---- in-register softmax over m (128) per node ----
        #pragma unroll
        for (int bt = 0; bt < 2; ++bt) {
            float mx = acc[0][bt][0];
            #pragma unroll
            for (int ai = 0; ai < 2; ++ai)
                #pragma unroll
                for (int r = 0; r < 4; ++r) mx = fmaxf(mx, acc[ai][bt][r]);
            mx = fmaxf(mx, __shfl_xor(mx, 16));
            mx = fmaxf(mx, __shfl_xor(mx, 32));
            float sm = 0.f;
            #pragma unroll
            for (int ai = 0; ai < 2; ++ai)
                #pragma unroll
                for (int r = 0; r < 4; ++r) sm += __expf(acc[ai][bt][r] - mx);
            sm += __shfl_xor(sm, 16);
            sm += __shfl_xor(sm, 32);
            if (l4 == 0) s_part[(wv * 2 + bt) * 16 + l15] = make_float2(mx, sm);
        }
        __syncthreads();
        #pragma unroll
        for (int bt = 0; bt < 2; ++bt) {
            const float2 p0 = s_part[(0 * 2 + bt) * 16 + l15];
            const float2 p1 = s_part[(1 * 2 + bt) * 16 + l15];
            const float2 p2 = s_part[(2 * 2 + bt) * 16 + l15];
            const float2 p3 = s_part[(3 * 2 + bt) * 16 + l15];
            const float mg = fmaxf(fmaxf(p0.x, p1.x), fmaxf(p2.x, p3.x));
            const float sg = p0.y * __expf(p0.x - mg) + p1.y * __expf(p1.x - mg)
                           + p2.y * __expf(p2.x - mg) + p3.y * __expf(p3.x - mg);
            const float inv = 1.f / sg;
            ushort_t* prow = s_P + (bt * 16 + l15) * PSTR + (wv * 2) * 16 + l4 * 4;
            #pragma unroll
            for (int ai = 0; ai < 2; ++ai)
                #pragma unroll
                for (int r = 0; r < 4; ++r)
                    prow[ai * 16 + r] = f32_bf16(__expf(acc[ai][bt][r] - mg) * inv);
        }
    }
    __syncthreads();

    // ====== PV: attn = P @ Mv (N=320); mix = 0.5*(attn+ln) -> s_lnh =========
    {
        f32x4 acc[2][5];
        #pragma unroll
        for (int mt = 0; mt < 2; ++mt)
            #pragma unroll
            for (int nn = 0; nn < 5; ++nn) acc[mt][nn] = zero4;

        #pragma unroll
        for (int kc = 0; kc < 4; ++kc) {
            const int koff = kc * 32 + l4 * 8;
            short8 ap[2];
            #pragma unroll
            for (int mt = 0; mt < 2; ++mt)
                ap[mt] = *(const short8*)(s_P + (mt * 16 + l15) * PSTR + koff);
            short8 bv[5];
            #pragma unroll
            for (int nn = 0; nn < 5; ++nn) {
                const int c = (wv * 5 + nn) * 16 + l15;
                bv[nn] = *(const short8*)(mv_t + (size_t)c * MEMN + koff);
            }
            #pragma unroll
            for (int mt = 0; mt < 2; ++mt)
                #pragma unroll
                for (int nn = 0; nn < 5; ++nn)
                    acc[mt][nn] = __builtin_amdgcn_mfma_f32_16x16x32_bf16(ap[mt], bv[nn], acc[mt][nn], 0, 0, 0);
        }
        // mix: unique owner lane per (node,c) -> in-place safe. lnv = hi + lo.
        #pragma unroll
        for (int mt = 0; mt < 2; ++mt)
            #pragma unroll
            for (int nn = 0; nn < 5; ++nn)
                #pragma unroll
                for (int r = 0; r < 4; ++r) {
                    const int node_l = mt * 16 + l4 * 4 + r;
                    const int c = (wv * 5 + nn) * 16 + l15;
                    const int idx = node_l * MSTR + c;
                    const float lnv = bf16_f32(s_lnh[idx]) + bf16_f32(s_lnl[idx]);
                    s_lnh[idx] = f32_bf16(0.5f * (acc[mt][nn][r] + lnv));
                }
    }
    __syncthreads();

    // ================= W1: h = relu(mix @ W1 + b1) -> s_P ====================
    {
        f32x4 acc[2][2];
        #pragma unroll
        for (int mt = 0; mt < 2; ++mt)
            #pragma unroll
            for (int nt = 0; nt < 2; ++nt) acc[mt][nt] = zero4;

        #pragma unroll 2
        for (int kc = 0; kc < 10; ++kc) {
            const int koff = kc * 32 + l4 * 8;
            short8 am[2], bw[2];
            #pragma unroll
            for (int mt = 0; mt < 2; ++mt)
                am[mt] = *(const short8*)(s_lnh + (mt * 16 + l15) * MSTR + koff);
            #pragma unroll
            for (int nt = 0; nt < 2; ++nt) {
                const int n = (wv * 2 + nt) * 16 + l15;
                bw[nt] = *(const short8*)(w1_t + (size_t)n * CATN + koff);
            }
            #pragma unroll
            for (int mt = 0; mt < 2; ++mt)
                #pragma unroll
                for (int nt = 0; nt < 2; ++nt)
                    acc[mt][nt] = __builtin_amdgcn_mfma_f32_16x16x32_bf16(am[mt], bw[nt], acc[mt][nt], 0, 0, 0);
        }
        float bb[2];
        #pragma unroll
        for (int nt = 0; nt < 2; ++nt) bb[nt] = b1[(wv * 2 + nt) * 16 + l15];
        __syncthreads();   // all W1 A-reads done before s_P region is reused as h
        #pragma unroll
        for (int mt = 0; mt < 2; ++mt)
            #pragma unroll
            for (int nt = 0; nt < 2; ++nt)
                #pragma unroll
                for (int r = 0; r < 4; ++r) {
                    const int node_l = mt * 16 + l4 * 4 + r;
                    const int col = (wv * 2 + nt) * 16 + l15;
                    s_P[node_l * PSTR + col] = f32_bf16(fmaxf(acc[mt][nt][r] + bb[nt], 0.f));
                }
    }
    __syncthreads();

    // ================= W2: y = h @ W2 + b2 -> out ============================
    {
        f32x4 acc[2][2];
        #pragma unroll
        for (int mt = 0; mt < 2; ++mt)
            #pragma unroll
            for (int nt = 0; nt < 2; ++nt) acc[mt][nt] = zero4;

        #pragma unroll
        for (int kc = 0; kc < 4; ++kc) {
            const int koff = kc * 32 + l4 * 8;
            short8 ah[2], bw[2];
            #pragma unroll
            for (int mt = 0; mt < 2; ++mt)
                ah[mt] = *(const short8*)(s_P + (mt * 16 + l15) * PSTR + koff);
            #pragma unroll
            for (int nt = 0; nt < 2; ++nt) {
                const int n = (wv * 2 + nt) * 16 + l15;
                bw[nt] = *(const short8*)(w2_t + (size_t)n * HIDN + koff);
            }
            #pragma unroll
            for (int mt = 0; mt < 2; ++mt)
                #pragma unroll
                for (int nt = 0; nt < 2; ++nt)
                    acc[mt][nt] = __builtin_amdgcn_mfma_f32_16x16x32_bf16(ah[mt], bw[nt], acc[mt][nt], 0, 0, 0);
        }
        float bb[2];
        #pragma unroll
        for (int nt = 0; nt < 2; ++nt) bb[nt] = b2[(wv * 2 + nt) * 16 + l15];
        #pragma unroll
        for (int mt = 0; mt < 2; ++mt)
            #pragma unroll
            for (int nt = 0; nt < 2; ++nt)
                #pragma unroll
                for (int r = 0; r < 4; ++r) {
                    const int ng = node0 + mt * 16 + l4 * 4 + r;
                    if (ng < NN) {
                        const int col = (wv * 2 + nt) * 16 + l15;
                        out[(size_t)ng * HIDN + col] = acc[mt][nt][r] + bb[nt];
                    }
                }
    }
}

// ---------------------------------------------------------------------------
extern "C" void kernel_launch(void* const* d_in, const int* in_sizes, int n_in,
                              void* d_out, int out_size, void* d_ws, size_t ws_size,
                              hipStream_t stream)
{
    const float* x         = (const float*)d_in[0];
    const int*   edge_idx  = (const int*)  d_in[1];   // [2,E] int32
    const float* edge_attr = (const float*)d_in[2];
    const float* u         = (const float*)d_in[3];
    const int*   batch     = (const int*)  d_in[4];
    const float* Mk        = (const float*)d_in[5];
    const float* Mv        = (const float*)d_in[6];
    const float* gamma     = (const float*)d_in[7];
    const float* beta      = (const float*)d_in[8];
    const float* W1        = (const float*)d_in[9];
    const float* b1        = (const float*)d_in[10];
    const float* W2        = (const float*)d_in[11];
    const float* b2        = (const float*)d_in[12];
    float*       out       = (float*)d_out;

    // ws layout
    char* w = (char*)d_ws;
    int*   count     = (int*)w;        w += (size_t)NN * sizeof(int);
    int*   cursor    = (int*)w;        w += (size_t)NN * sizeof(int);
    int*   offsets   = (int*)w;        w += (size_t)NN * sizeof(int);
    int*   partials  = (int*)w;        w += 256 * sizeof(int);
    int*   bucket    = (int*)w;        w += (size_t)EE * sizeof(int);              // 3.2 MB
    w = (char*)(((size_t)w + 255) & ~(size_t)255);
    unsigned* ln_pk  = (unsigned*)w;   w += (size_t)NN * CATN * sizeof(unsigned);  // 64 MB
    ushort_t* mk_hi  = (ushort_t*)w;   w += (size_t)MEMN * CATN * 2;
    ushort_t* mk_lo  = (ushort_t*)w;   w += (size_t)MEMN * CATN * 2;
    ushort_t* mv_t   = (ushort_t*)w;   w += (size_t)CATN * MEMN * 2;
    ushort_t* w1_t   = (ushort_t*)w;   w += (size_t)HIDN * CATN * 2;
    ushort_t* w2_t   = (ushort_t*)w;   w += (size_t)HIDN * HIDN * 2;

    const int* edge_dst = edge_idx + EE;         // row 1 of edge_index

    hipMemsetAsync(count, 0, (size_t)2 * NN * sizeof(int), stream);

    const int eb = (EE + 255) / 256;
    hist_kernel<<<eb, 256, 0, stream>>>(edge_dst, count);
    block_sum_kernel<<<SCAN_NB, 256, 0, stream>>>(count, partials);
    scan_partials_kernel<<<1, 256, 0, stream>>>(partials);
    make_offsets_kernel<<<SCAN_NB, 256, 0, stream>>>(count, partials, offsets);
    fill_kernel<<<eb, 256, 0, stream>>>(edge_dst, offsets, cursor, bucket);

    prep_all_kernel<<<(HIDN * CATN + 255) / 256, 256, 0, stream>>>(
        Mk, Mv, W1, W2, mk_hi, mk_lo, mv_t, w1_t, w2_t);

    gather_ln_kernel<<<(NN * 64 + 255) / 256, 256, 0, stream>>>(
        edge_attr, bucket, offsets, count, x, u, batch, gamma, beta, ln_pk);

    node_mfma_kernel<<<(NN + 31) / 32, 256, 0, stream>>>(
        ln_pk, mk_hi, mk_lo, mv_t, w1_t, w2_t, b1, b2, out);
}